// Round 8
// baseline (589.372 us; speedup 1.0000x reference)
//
#include <hip/hip_runtime.h>
#include <math.h>
#include <stdint.h>

// Problem: B=4, S=4096, D=2048, E=64, TOP_K=2
#define M_TOK  16384
#define D_DIM  2048
#define E_EXP  64
#define KCC    4
#define KCHUNK (D_DIM / KCC)      // 512
#define NCOL   128                // [route 64 | noise 64]
#define TAU    1e-3f              // flag threshold on top-3 gaps (fast-path error ~3e-5 -> 30x margin)
#define EP_TOK 32                 // tokens per epilogue block

typedef __bf16    bf16x8 __attribute__((ext_vector_type(8)));
typedef float     f32x16 __attribute__((ext_vector_type(16)));
typedef uint32_t  u32x4  __attribute__((ext_vector_type(4)));

// ---- workspace layout (bytes): ONLY write-then-read-within-call data ----
#define OFF_BH    0                                // bf16 hi frags [D/8][128][8]
#define OFF_BL    (OFF_BH + (D_DIM/8)*NCOL*16)     // bf16 lo frags
#define OFF_SLAB  (2*1024*1024)                    // f32 partials [KCC][M][128]
#define SLAB_STRIDE ((size_t)M_TOK * NCOL)

// ---------------- stage 0: W -> B-fragment-ordered bf16 hi/lo ----------------
__global__ __launch_bounds__(256) void build_bfrag(const float* __restrict__ Wr,
                                                   const float* __restrict__ Wn,
                                                   char* __restrict__ ws) {
    const int id = blockIdx.x * 256 + threadIdx.x;   // 0..32767 = kb*128+n
    const int kb = id >> 7;
    const int n  = id & 127;
    const float* src = (n < 64) ? (Wr + n) : (Wn + n - 64);
    u32x4 hp, lp;
    #pragma unroll
    for (int p = 0; p < 4; ++p) {
        const float w0 = src[(size_t)(kb * 8 + 2*p)     * E_EXP];
        const float w1 = src[(size_t)(kb * 8 + 2*p + 1) * E_EXP];
        const uint32_t u0 = __float_as_uint(w0), u1 = __float_as_uint(w1);
        const uint32_t h0 = u0 & 0xFFFF0000u,    h1 = u1 & 0xFFFF0000u;
        const float lo0 = w0 - __uint_as_float(h0);
        const float lo1 = w1 - __uint_as_float(h1);
        hp[p] = (u0 >> 16) | h1;
        lp[p] = (__float_as_uint(lo0) >> 16) | (__float_as_uint(lo1) & 0xFFFF0000u);
    }
    *(u32x4*)(ws + OFF_BH + (size_t)id * 16) = hp;
    *(u32x4*)(ws + OFF_BL + (size_t)id * 16) = lp;
}

// ---------------- stage 1: bf16x2-split MFMA GEMM, f32 partials ----------------
// HOT-LOOP RULE (rounds 4+5 lesson): NO arrays/unions/variable-indexed aggregates.
// R4: 164 live VGPRs -> scratch spill @124. R5: a4[2][2] -> PromoteAlloca to LDS.
// Named scalars + __builtin_bit_cast only; pipeline rotation via SSA assignment.
// MFMA 32x32x16_bf16 layouts (measured, learn_hip m74/m101):
//   A[m][k]: m=lane&31, k=(lane>>5)*8+j ; B[k][n]: n=lane&31, same k
//   C/D: col=lane&31, row=(reg&3)+8*(reg>>2)+4*(lane>>5)
__device__ __forceinline__ void split2(float x0, float x1, uint32_t& hp, uint32_t& lp) {
    const uint32_t u0 = __float_as_uint(x0), u1 = __float_as_uint(x1);
    const uint32_t h0 = u0 & 0xFFFF0000u,    h1 = u1 & 0xFFFF0000u;
    const float lo0 = x0 - __uint_as_float(h0);   // exact residual
    const float lo1 = x1 - __uint_as_float(h1);
    hp = (u0 >> 16) | h1;
    lp = (__float_as_uint(lo0) >> 16) | (__float_as_uint(lo1) & 0xFFFF0000u);
}

__global__ __launch_bounds__(256, 3) void gemm_fast(const float* __restrict__ A,
                                                    char* __restrict__ ws) {
    const int tile = blockIdx.x & 255;
    const int kc   = blockIdx.x >> 8;
    const int tid  = threadIdx.x;
    const int w    = tid >> 6;
    const int lane = tid & 63;
    const int half = lane >> 5;
    const int l32  = lane & 31;
    const int tg   = w >> 1;            // token group
    const int cg   = w & 1;             // col group (cols cg*64 .. +63)
    const int tokBase = tile * 64 + tg * 32;
    const int k0      = kc * KCHUNK;

    const float* Ap = A + (size_t)(tokBase + l32) * D_DIM + k0 + half * 8;
    const char* BHb = ws + OFF_BH + (((size_t)(k0 >> 3) + half) * NCOL + cg * 64 + l32) * 16;
    const char* BLb = ws + OFF_BL + (((size_t)(k0 >> 3) + half) * NCOL + cg * 64 + l32) * 16;

    f32x16 acc0, acc1;
    #pragma unroll
    for (int i = 0; i < 16; ++i) { acc0[i] = 0.f; acc1[i] = 0.f; }

    // software pipeline: current-step regs loaded, next-step prefetched in loop
    float4 ca0 = *(const float4*)(Ap);
    float4 ca1 = *(const float4*)(Ap + 4);
    bf16x8 cb0h = *(const bf16x8*)(BHb);
    bf16x8 cb1h = *(const bf16x8*)(BHb + 512);
    bf16x8 cb0l = *(const bf16x8*)(BLb);
    bf16x8 cb1l = *(const bf16x8*)(BLb + 512);

    #pragma unroll 4
    for (int s = 0; s < KCHUNK / 16; ++s) {          // 32 K16-steps
        float4 na0, na1;
        bf16x8 nb0h, nb1h, nb0l, nb1l;
        if (s < KCHUNK / 16 - 1) {
            const float* apn = Ap + (s + 1) * 16;
            na0 = *(const float4*)(apn);
            na1 = *(const float4*)(apn + 4);
            const char* bhn = BHb + (size_t)(s + 1) * 4096;  // step advances kb by 2
            const char* bln = BLb + (size_t)(s + 1) * 4096;
            nb0h = *(const bf16x8*)(bhn);
            nb1h = *(const bf16x8*)(bhn + 512);
            nb0l = *(const bf16x8*)(bln);
            nb1l = *(const bf16x8*)(bln + 512);
        }

        u32x4 ahu, alu;
        uint32_t h, l;
        split2(ca0.x, ca0.y, h, l); ahu[0] = h; alu[0] = l;
        split2(ca0.z, ca0.w, h, l); ahu[1] = h; alu[1] = l;
        split2(ca1.x, ca1.y, h, l); ahu[2] = h; alu[2] = l;
        split2(ca1.z, ca1.w, h, l); ahu[3] = h; alu[3] = l;
        const bf16x8 Ah = __builtin_bit_cast(bf16x8, ahu);
        const bf16x8 Al = __builtin_bit_cast(bf16x8, alu);

        acc0 = __builtin_amdgcn_mfma_f32_32x32x16_bf16(Ah, cb0h, acc0, 0, 0, 0);
        acc0 = __builtin_amdgcn_mfma_f32_32x32x16_bf16(Ah, cb0l, acc0, 0, 0, 0);
        acc0 = __builtin_amdgcn_mfma_f32_32x32x16_bf16(Al, cb0h, acc0, 0, 0, 0);
        acc1 = __builtin_amdgcn_mfma_f32_32x32x16_bf16(Ah, cb1h, acc1, 0, 0, 0);
        acc1 = __builtin_amdgcn_mfma_f32_32x32x16_bf16(Ah, cb1l, acc1, 0, 0, 0);
        acc1 = __builtin_amdgcn_mfma_f32_32x32x16_bf16(Al, cb1h, acc1, 0, 0, 0);

        ca0 = na0; ca1 = na1;                         // SSA rotation (no arrays)
        cb0h = nb0h; cb1h = nb1h; cb0l = nb0l; cb1l = nb1l;
    }

    float* slab = (float*)(ws + OFF_SLAB) + (size_t)kc * SLAB_STRIDE;
    {
        const int col0 = cg * 64 + l32;
        #pragma unroll
        for (int r = 0; r < 16; ++r) {
            const int row = (r & 3) + 8 * (r >> 2) + 4 * half;
            slab[(size_t)(tokBase + row) * NCOL + col0] = acc0[r];
        }
        const int col1 = cg * 64 + 32 + l32;
        #pragma unroll
        for (int r = 0; r < 16; ++r) {
            const int row = (r & 3) + 8 * (r >> 2) + 4 * half;
            slab[(size_t)(tokBase + row) * NCOL + col1] = acc1[r];
        }
    }
}

// ---------------- stage 2: sum partials + fp32 top-3 + in-block f64 recheck ----------------
__device__ __forceinline__ void ins3(float v, int i,
                                     float& v0, int& i0, float& v1, int& i1, float& v2, int& i2) {
    if (v > v0 || (v == v0 && i < i0))      { v2=v1; i2=i1; v1=v0; i1=i0; v0=v; i0=i; }
    else if (v > v1 || (v == v1 && i < i1)) { v2=v1; i2=i1; v1=v; i1=i; }
    else if (v > v2 || (v == v2 && i < i2)) { v2=v; i2=i; }
}

__global__ __launch_bounds__(256) void epilogue(const char* __restrict__ ws,
                                                const float* __restrict__ A,
                                                const float* __restrict__ Wr,
                                                const float* __restrict__ Wn,
                                                const float* __restrict__ br,
                                                const float* __restrict__ bn,
                                                const float* __restrict__ noise,
                                                float* __restrict__ probs,
                                                float* __restrict__ idx_out) {
    __shared__ int    flagCnt;
    __shared__ int    flagList[EP_TOK];
    __shared__ double red[256];

    const int tid   = threadIdx.x;
    const int t_loc = tid >> 3;                // token within block (0..31)
    const int p     = tid & 7;                 // col octet: cols p*8 .. p*8+7
    const int token = blockIdx.x * EP_TOK + t_loc;
    const int base  = p * 8;
    const float* slab = (const float*)(ws + OFF_SLAB);

    if (tid == 0) flagCnt = 0;
    __syncthreads();

    float lr[8], ln[8];
    #pragma unroll
    for (int j = 0; j < 8; ++j) { lr[j] = 0.f; ln[j] = 0.f; }
    #pragma unroll
    for (int kcv = 0; kcv < KCC; ++kcv) {
        const float* q = slab + (size_t)kcv * SLAB_STRIDE + (size_t)token * NCOL + base;
        const float4 a0 = *(const float4*)(q);
        const float4 a1 = *(const float4*)(q + 4);
        const float4 b0 = *(const float4*)(q + 64);
        const float4 b1 = *(const float4*)(q + 68);
        lr[0] += a0.x; lr[1] += a0.y; lr[2] += a0.z; lr[3] += a0.w;
        lr[4] += a1.x; lr[5] += a1.y; lr[6] += a1.z; lr[7] += a1.w;
        ln[0] += b0.x; ln[1] += b0.y; ln[2] += b0.z; ln[3] += b0.w;
        ln[4] += b1.x; ln[5] += b1.y; ln[6] += b1.z; ln[7] += b1.w;
    }

    const float* nz = noise + (size_t)token * E_EXP + base;
    const float4 n0 = *(const float4*)(nz);
    const float4 n1 = *(const float4*)(nz + 4);

    float v0 = -INFINITY, v1 = -INFINITY, v2 = -INFINITY;
    int   i0 = 999, i1 = 999, i2 = 999;
    #pragma unroll
    for (int j = 0; j < 8; ++j) {
        const int e = base + j;
        const float nzj = (j < 4) ? ((j==0)?n0.x:(j==1)?n0.y:(j==2)?n0.z:n0.w)
                                  : ((j==4)?n1.x:(j==5)?n1.y:(j==6)?n1.z:n1.w);
        const float lnn = ln[j] + bn[e];
        const float sp  = fmaxf(lnn, 0.f) + log1pf(expf(-fabsf(lnn)));
        const float v   = fmaf(nzj, sp, lr[j] + br[e]);
        ins3(v, e, v0, i0, v1, i1, v2, i2);
    }
    #pragma unroll
    for (int m = 1; m < 8; m <<= 1) {          // merge across the token's 8 lanes
        const float w0 = __shfl_xor(v0, m), w1 = __shfl_xor(v1, m), w2 = __shfl_xor(v2, m);
        const int   j0 = __shfl_xor(i0, m), j1 = __shfl_xor(i1, m), j2 = __shfl_xor(i2, m);
        ins3(w0, j0, v0, i0, v1, i1, v2, i2);
        ins3(w1, j1, v0, i0, v1, i1, v2, i2);
        ins3(w2, j2, v0, i0, v1, i1, v2, i2);
    }

    const float e1  = expf(v1 - v0);
    const float den = 1.f + e1;
    const float pp0 = 1.f / den, pp1 = e1 / den;
    float* pb = probs + (size_t)token * E_EXP + base;
    {
        float4 o0, o1;
        o0.x = (base+0 == i0) ? pp0 : ((base+0 == i1) ? pp1 : 0.f);
        o0.y = (base+1 == i0) ? pp0 : ((base+1 == i1) ? pp1 : 0.f);
        o0.z = (base+2 == i0) ? pp0 : ((base+2 == i1) ? pp1 : 0.f);
        o0.w = (base+3 == i0) ? pp0 : ((base+3 == i1) ? pp1 : 0.f);
        o1.x = (base+4 == i0) ? pp0 : ((base+4 == i1) ? pp1 : 0.f);
        o1.y = (base+5 == i0) ? pp0 : ((base+5 == i1) ? pp1 : 0.f);
        o1.z = (base+6 == i0) ? pp0 : ((base+6 == i1) ? pp1 : 0.f);
        o1.w = (base+7 == i0) ? pp0 : ((base+7 == i1) ? pp1 : 0.f);
        *(float4*)(pb)     = o0;
        *(float4*)(pb + 4) = o1;
    }
    if (p == 0) {
        *(float2*)(idx_out + (size_t)token * 2) = make_float2((float)i0, (float)i1);
        if ((v0 - v1 < TAU) || (v1 - v2 < TAU)) {      // ambiguous -> exact in-block recheck
            const int pos = atomicAdd(&flagCnt, 1);    // LDS atomic, block-local
            flagList[pos] = t_loc;
        }
    }
    __syncthreads();   // flags visible; fast-path stores drained before overwrite below

    // ---- exact f64 recheck of this block's flagged tokens (all 256 threads) ----
    const int nf = flagCnt;
    const int e  = tid & 63;
    const int m  = (tid >> 6) & 1;
    const int h  = tid >> 7;
    const float* W = m ? Wn : Wr;
    for (int f = 0; f < nf; ++f) {
        const int tok2 = blockIdx.x * EP_TOK + flagList[f];
        const float* ar = A + (size_t)tok2 * D_DIM + h * 1024;
        const float* wp = W + (size_t)h * 1024 * E_EXP + e;
        double p0 = 0.0, p1 = 0.0, p2 = 0.0, p3 = 0.0;   // 4-deep ILP (chain 256)
        #pragma unroll 4
        for (int k = 0; k < 1024; k += 4) {
            p0 = fma((double)ar[k],     (double)wp[(size_t)k * E_EXP],       p0);
            p1 = fma((double)ar[k + 1], (double)wp[(size_t)(k + 1) * E_EXP], p1);
            p2 = fma((double)ar[k + 2], (double)wp[(size_t)(k + 2) * E_EXP], p2);
            p3 = fma((double)ar[k + 3], (double)wp[(size_t)(k + 3) * E_EXP], p3);
        }
        red[tid] = (p0 + p1) + (p2 + p3);
        __syncthreads();
        if (tid < 64) {
            const double lrv = red[tid] + red[tid + 128] + (double)br[e];
            const double lnv = red[tid + 64] + red[tid + 192] + (double)bn[e];
            const double sp  = fmax(lnv, 0.0) + log1p(exp(-fabs(lnv)));
            const double v   = fma((double)noise[(size_t)tok2 * E_EXP + e], sp, lrv);
            double a0 = v, a1 = -INFINITY;
            int    j0 = e, j1 = 999;
            #pragma unroll
            for (int msk = 1; msk < 64; msk <<= 1) {
                const double w0 = __shfl_xor(a0, msk), w1 = __shfl_xor(a1, msk);
                const int    q0 = __shfl_xor(j0, msk), q1 = __shfl_xor(j1, msk);
                if ((a0 > w0) || (a0 == w0 && j0 < q0)) {
                    if (!((a1 > w0) || (a1 == w0 && j1 < q0))) { a1 = w0; j1 = q0; }
                } else {
                    if ((a0 > w1) || (a0 == w1 && j0 < q1)) { a1 = a0; j1 = j0; }
                    else                                    { a1 = w1; j1 = q1; }
                    a0 = w0; j0 = q0;
                }
            }
            const double ex = exp(a1 - a0);
            const double dn = 1.0 + ex;
            const float q0f = (float)(1.0 / dn), q1f = (float)(ex / dn);
            probs[(size_t)tok2 * E_EXP + tid] = (tid == j0) ? q0f : ((tid == j1) ? q1f : 0.f);
            if (tid == 0)
                *(float2*)(idx_out + (size_t)tok2 * 2) = make_float2((float)j0, (float)j1);
        }
        __syncthreads();
    }
}

extern "C" void kernel_launch(void* const* d_in, const int* in_sizes, int n_in,
                              void* d_out, int out_size, void* d_ws, size_t ws_size,
                              hipStream_t stream) {
    (void)in_sizes; (void)n_in; (void)out_size; (void)ws_size;
    const float* A  = (const float*)d_in[0];
    const float* Wr = (const float*)d_in[1];
    const float* br = (const float*)d_in[2];
    const float* Wn = (const float*)d_in[3];
    const float* bn = (const float*)d_in[4];
    const float* nz = (const float*)d_in[5];

    float* probs = (float*)d_out;                    // [4,4096,64] f32
    float* idxo  = probs + (size_t)M_TOK * E_EXP;    // [4,4096,2] as f32
    char*  ws    = (char*)d_ws;                      // ~36 MB used

    build_bfrag<<<128, 256, 0, stream>>>(Wr, Wn, ws);
    gemm_fast<<<256 * KCC, 256, 0, stream>>>(A, ws);
    epilogue<<<M_TOK / EP_TOK, 256, 0, stream>>>(ws, A, Wr, Wn, br, bn, nz, probs, idxo);
}